// Round 7
// baseline (491.767 us; speedup 1.0000x reference)
//
#include <hip/hip_runtime.h>
#include <hip/hip_bf16.h>
#include <float.h>
#include <stdint.h>

#define N_ROWS 16384
#define DIM 256
#define NE 8192
#define K2 768
#define DECAY 0.8f
#define OMD 0.2f
#define EPS 1e-5f
#define NPAN 8
#define NKT 24
#define NVT 96

// ---- ws layout (float element offsets) ----
#define WS_X2     0            // 16384*768 bf16 (6291456 floats)
#define WS_EMBEDT 0            // overlay (after argmin): 8192*256 f32
#define WS_ESUMT  2097152      // overlay (after argmin): 8192*256 f32
#define WS_B2T    6291456      // 8192*768 bf16 (3145728 floats)
#define WS_ENORM  9437184      // 8192
#define WS_COUNTS 9445376      // 8192
#define WS_SMOOTH 9453568      // 8192
#define WS_PI     9592832      // 16384*8 (int)
#define WS_LOSS   9740288      // 1
#define WS_TOTAL  9740289      // 1

// ---- out layout (float element offsets) ----
#define OUT_Q    0
#define OUT_IND  4194304
#define OUT_LOSS 4210688
#define OUT_NE   4210689
#define OUT_NCS  6307841
#define OUT_NEA  6316033

typedef __attribute__((ext_vector_type(8))) short bf16x8;
typedef __attribute__((ext_vector_type(4))) float f32x4;

static __device__ __forceinline__ ushort f2bf(float f) {
    uint32_t u = __float_as_uint(f);
    uint32_t r = (u + 0x7fffu + ((u >> 16) & 1u)) >> 16;
    return (ushort)r;
}
static __device__ __forceinline__ float bf2f(ushort h) {
    return __uint_as_float(((uint32_t)h) << 16);
}
static __device__ __forceinline__ void async16(void* lds, const void* g) {
    __builtin_amdgcn_global_load_lds(
        (const __attribute__((address_space(1))) uint32_t*)g,
        (__attribute__((address_space(3))) uint32_t*)lds, 16, 0, 0);
}

// x [16384][256] f32 -> X2 [16384][768] bf16 = [hi | lo | hi]
__global__ __launch_bounds__(256) void convx_kernel(const float* __restrict__ x,
                                                    ushort* __restrict__ X2) {
    int i = blockIdx.x * 256 + threadIdx.x;
    int row = i >> 6, q = (i & 63) * 4;
    float4 v = *(const float4*)&x[(size_t)row * 256 + q];
    ushort4 hi, lo;
    hi.x = f2bf(v.x); hi.y = f2bf(v.y); hi.z = f2bf(v.z); hi.w = f2bf(v.w);
    lo.x = f2bf(v.x - bf2f(hi.x)); lo.y = f2bf(v.y - bf2f(hi.y));
    lo.z = f2bf(v.z - bf2f(hi.z)); lo.w = f2bf(v.w - bf2f(hi.w));
    *(ushort4*)&X2[(size_t)row * K2 + q]       = hi;
    *(ushort4*)&X2[(size_t)row * K2 + 256 + q] = lo;
    *(ushort4*)&X2[(size_t)row * K2 + 512 + q] = hi;
}

// fused: embed [256][8192] -> B2T [8192][768] bf16 [hi|hi|lo]  +  enorm partials
__global__ __launch_bounds__(256) void prepB_kernel(const float* __restrict__ embed,
                                                    ushort* __restrict__ B2T,
                                                    float* __restrict__ enorm) {
    __shared__ float t[32][33];
    int c0 = blockIdx.x * 32, d0 = blockIdx.y * 32;
    int tx = threadIdx.x & 31, ty = threadIdx.x >> 5;
    #pragma unroll
    for (int r = 0; r < 4; ++r)
        t[ty + r * 8][tx] = embed[(size_t)(d0 + ty + r * 8) * NE + c0 + tx];
    __syncthreads();
    #pragma unroll
    for (int r = 0; r < 4; ++r) {
        int c = c0 + ty + r * 8, d = d0 + tx;
        float v = t[tx][ty + r * 8];
        ushort hi = f2bf(v);
        ushort lo = f2bf(v - bf2f(hi));
        B2T[(size_t)c * K2 + d]       = hi;
        B2T[(size_t)c * K2 + 256 + d] = hi;
        B2T[(size_t)c * K2 + 512 + d] = lo;
        float s = v * v;
        #pragma unroll
        for (int off = 16; off; off >>= 1) s += __shfl_down(s, off, 32);
        if (tx == 0) atomicAdd(&enorm[c], s);
    }
}

// embed [DIM][NE] -> embedT [NE][DIM]  (f32, for exact rerank; overlays X2)
__global__ __launch_bounds__(256) void transpose_kernel(const float* __restrict__ embed,
                                                        float* __restrict__ embedT) {
    __shared__ float t[32][33];
    int c0 = blockIdx.x * 32, d0 = blockIdx.y * 32;
    int tx = threadIdx.x & 31, ty = threadIdx.x >> 5;
    #pragma unroll
    for (int r = 0; r < 4; ++r)
        t[ty + r * 8][tx] = embed[(size_t)(d0 + ty + r * 8) * NE + c0 + tx];
    __syncthreads();
    #pragma unroll
    for (int r = 0; r < 4; ++r)
        embedT[(size_t)(c0 + ty + r * 8) * DIM + d0 + tx] = t[tx][ty + r * 8];
}

#define MFMA16(d, a, b) d = __builtin_amdgcn_mfma_f32_16x16x32_bf16(a, b, d, 0, 0, 0)

// 256x256 tile, 8 waves (128x64 each), BK=32, triple-buffered LDS.
// Same pipeline as R6 (issue vt+2; vmcnt(8); 2 barriers/iter), new geometry:
// 32 independent MFMAs/iter/wave, 96KB LDS-read/iter/CU (was 128KB),
// 2-way-only bank aliasing via (row>>2)-based XOR swizzle (free per m136).
__global__ __launch_bounds__(512, 2) void argmin_mfma(
    const ushort* __restrict__ X2, const ushort* __restrict__ B2T,
    const float* __restrict__ enorm, int* __restrict__ pi) {
    // ushort units: A bufs 3x8192 | B bufs 3x8192 | redv | redc | enS
    __shared__ ushort smem[55296];
    float* const redv = (float*)(smem + 49152);
    int*   const redc = (int*)(smem + 51200);
    float* const enS  = (float*)(smem + 53248);

    const int lin = blockIdx.x;
    const int by = lin & 7, bx = lin >> 3;     // round-robin: XCD k owns panel k
    const int row0 = bx * 256, colb = by * 1024;

    const int tid = threadIdx.x;
    const int lane = tid & 63, wid = tid >> 6;
    const int fl = lane & 15, fh = lane >> 4;
    const int wr = wid >> 2, wc = wid & 3;     // 2 x 4 waves -> 128x64 tiles

    enS[tid] = enorm[colb + tid];
    enS[tid + 512] = enorm[colb + 512 + tid];
    redv[tid] = FLT_MAX;       redc[tid] = 0x7fffffff;
    redv[tid + 512] = FLT_MAX; redc[tid + 512] = 0x7fffffff;

    // staging: chunk c = tid + j*512 (j=0,1): row = c>>2, slot = tid&3
    // LDS[row][s] = G[row][s ^ ((row>>2)&3)]; (row>>2)&3 == (tid>>4)&3 for both j
    const int srow = tid >> 2;
    const int swz = (tid & 3) ^ ((tid >> 4) & 3);
    const size_t aB = (size_t)(row0 + srow) * K2 + swz * 8;
    const size_t bB = (size_t)(colb + srow) * K2 + swz * 8;
    const size_t jA = (size_t)128 * K2;        // +128 rows for chunk j=1

    // prologue: tiles 0,1 -> bufs 0,1 (4 loads per tile per thread)
    #pragma unroll
    for (int tpre = 0; tpre < 2; ++tpre) {
        async16(smem + tpre * 8192 + tid * 8, X2 + aB + (size_t)tpre * 32);
        async16(smem + tpre * 8192 + (tid + 512) * 8, X2 + aB + jA + (size_t)tpre * 32);
        async16(smem + 24576 + tpre * 8192 + tid * 8, B2T + bB + (size_t)tpre * 32);
        async16(smem + 24576 + tpre * 8192 + (tid + 512) * 8, B2T + bB + jA + (size_t)tpre * 32);
    }

    const int xo = (fh ^ ((fl >> 2) & 3)) * 8;
    int aOff[8], bOff[4];
    #pragma unroll
    for (int m = 0; m < 8; ++m) aOff[m] = (wr * 128 + m * 16 + fl) * 32 + xo;
    #pragma unroll
    for (int n = 0; n < 4; ++n) bOff[n] = (wc * 64 + n * 16 + fl) * 32 + xo;

    f32x4 acc[8][4];
    #pragma unroll
    for (int m = 0; m < 8; ++m)
        #pragma unroll
        for (int n = 0; n < 4; ++n) acc[m][n] = (f32x4){0.f, 0.f, 0.f, 0.f};

    int cur = 0;
    #pragma unroll 1
    for (int vt = 0; vt < NVT; ++vt) {
        const int t = vt % NKT;
        int nv2 = vt + 2; if (nv2 >= NVT) nv2 -= NVT;
        const int nt2 = nv2 % NKT, nct2 = nv2 / NKT;
        int nbuf = cur + 2; if (nbuf >= 3) nbuf -= 3;

        // issue tile vt+2 into buf nbuf (freed at vt-1's end barrier)
        {
            const ushort* Xs = X2 + aB + (size_t)nt2 * 32;
            const ushort* Bs = B2T + bB + (size_t)nct2 * 196608 + (size_t)nt2 * 32;
            async16(smem + nbuf * 8192 + tid * 8, Xs);
            async16(smem + nbuf * 8192 + (tid + 512) * 8, Xs + jA);
            async16(smem + 24576 + nbuf * 8192 + tid * 8, Bs);
            async16(smem + 24576 + nbuf * 8192 + (tid + 512) * 8, Bs + jA);
        }

        asm volatile("s_waitcnt vmcnt(8)" ::: "memory");
        __builtin_amdgcn_s_barrier();
        __builtin_amdgcn_sched_barrier(0);

        const ushort* Ac = smem + cur * 8192;
        const ushort* Bc = smem + 24576 + cur * 8192;
        bf16x8 af[8], bf[4];
        #pragma unroll
        for (int n = 0; n < 4; ++n) bf[n] = *(const bf16x8*)&Bc[bOff[n]];
        #pragma unroll
        for (int m = 0; m < 8; ++m) af[m] = *(const bf16x8*)&Ac[aOff[m]];

        __builtin_amdgcn_s_setprio(1);
        #pragma unroll
        for (int m = 0; m < 8; ++m)
            #pragma unroll
            for (int n = 0; n < 4; ++n)
                MFMA16(acc[m][n], af[m], bf[n]);
        __builtin_amdgcn_s_setprio(0);

        if (t == NKT - 1) {
            const int ct = vt / NKT;
            const int cb = colb + ct * 256 + wc * 64;
            float en[4];
            #pragma unroll
            for (int n = 0; n < 4; ++n) en[n] = enS[ct * 256 + wc * 64 + n * 16 + fl];
            #pragma unroll
            for (int m = 0; m < 8; ++m)
                #pragma unroll
                for (int r = 0; r < 4; ++r) {
                    float bv = FLT_MAX; int bc = 0x7fffffff;
                    #pragma unroll
                    for (int n = 0; n < 4; ++n) {
                        float s = __builtin_fmaf(-2.f, acc[m][n][r], en[n]);
                        int c = cb + n * 16 + fl;
                        if (s < bv) { bv = s; bc = c; }
                    }
                    #pragma unroll
                    for (int off = 1; off < 16; off <<= 1) {
                        float ov = __shfl_xor(bv, off, 64);
                        int oc = __shfl_xor(bc, off, 64);
                        if (ov < bv || (ov == bv && oc < bc)) { bv = ov; bc = oc; }
                    }
                    if (fl == 0) {
                        const int slot = (wr * 128 + m * 16 + fh * 4 + r) * 4 + wc;
                        float cv = redv[slot]; int cc = redc[slot];
                        if (bv < cv || (bv == cv && bc < cc)) {
                            redv[slot] = bv; redc[slot] = bc;
                        }
                    }
                }
            #pragma unroll
            for (int m = 0; m < 8; ++m)
                #pragma unroll
                for (int n = 0; n < 4; ++n) acc[m][n] = (f32x4){0.f, 0.f, 0.f, 0.f};
        }
        __builtin_amdgcn_s_barrier();
        __builtin_amdgcn_sched_barrier(0);
        cur = cur + 1 == 3 ? 0 : cur + 1;
    }

    asm volatile("s_waitcnt vmcnt(0) lgkmcnt(0)" ::: "memory");
    __builtin_amdgcn_s_barrier();
    if (tid < 256) {
        float bv = redv[tid * 4]; int bc = redc[tid * 4];
        #pragma unroll
        for (int w = 1; w < 4; ++w) {
            float v = redv[tid * 4 + w]; int c = redc[tid * 4 + w];
            if (v < bv || (v == bv && c < bc)) { bv = v; bc = c; }
        }
        pi[(size_t)(row0 + tid) * NPAN + by] = bc;
    }
}

// fused exact-f32 rerank of the 8 panel winners + quantize/loss/EMA-scatter
__global__ __launch_bounds__(256) void rerank_gather(
    const float* __restrict__ x, const float* __restrict__ embedT,
    const int* __restrict__ pi, float* __restrict__ out_ind,
    float* __restrict__ q_out, float* __restrict__ esumT,
    float* __restrict__ counts, float* __restrict__ loss_acc) {
    const int row = blockIdx.x * 4 + (threadIdx.x >> 6);
    const int lane = threadIdx.x & 63;
    float4 xv = *(const float4*)&x[(size_t)row * DIM + lane * 4];
    float bestd = FLT_MAX; int besti = 0;
    float4 ebest = {0.f, 0.f, 0.f, 0.f};
    #pragma unroll
    for (int p = 0; p < NPAN; ++p) {           // candidate indices strictly increase with p
        const int c = pi[(size_t)row * NPAN + p];
        float4 e = *(const float4*)&embedT[(size_t)c * DIM + lane * 4];
        float dx = e.x - xv.x, dy = e.y - xv.y, dz = e.z - xv.z, dw = e.w - xv.w;
        float s = dx * dx + dy * dy + dz * dz + dw * dw;
        #pragma unroll
        for (int off = 32; off; off >>= 1) s += __shfl_down(s, off);
        s = __shfl(s, 0);
        if (s < bestd) { bestd = s; besti = c; ebest = e; }
    }
    *(float4*)&q_out[(size_t)row * DIM + lane * 4] = ebest;
    __shared__ float ls[4];
    if (lane == 0) {
        out_ind[row] = (float)besti;
        ls[threadIdx.x >> 6] = bestd;
        atomicAdd(&counts[besti], 1.0f);
    }
    atomicAdd(&esumT[(size_t)besti * DIM + lane * 4 + 0], xv.x);
    atomicAdd(&esumT[(size_t)besti * DIM + lane * 4 + 1], xv.y);
    atomicAdd(&esumT[(size_t)besti * DIM + lane * 4 + 2], xv.z);
    atomicAdd(&esumT[(size_t)besti * DIM + lane * 4 + 3], xv.w);
    __syncthreads();
    if (threadIdx.x == 0) atomicAdd(loss_acc, ls[0] + ls[1] + ls[2] + ls[3]);
}

__global__ void ncs_kernel(const float* __restrict__ cs, const float* __restrict__ counts,
                           float* __restrict__ out_ncs, float* __restrict__ total) {
    int c = blockIdx.x * 256 + threadIdx.x;
    float v = cs[c] * DECAY + counts[c] * OMD;
    out_ncs[c] = v;
    float s = v;
    #pragma unroll
    for (int off = 32; off; off >>= 1) s += __shfl_down(s, off);
    __shared__ float bs[4];
    if ((threadIdx.x & 63) == 0) bs[threadIdx.x >> 6] = s;
    __syncthreads();
    if (threadIdx.x == 0) atomicAdd(total, bs[0] + bs[1] + bs[2] + bs[3]);
}

__global__ void smooth_kernel(const float* __restrict__ out_ncs, const float* __restrict__ total,
                              float* __restrict__ smoothed, const float* __restrict__ loss_acc,
                              float* __restrict__ out_loss) {
    int c = blockIdx.x * 256 + threadIdx.x;
    float tot = *total;
    float v = out_ncs[c];
    smoothed[c] = (v + EPS) / (tot + (float)NE * EPS) * tot;
    if (blockIdx.x == 0 && threadIdx.x == 0)
        *out_loss = *loss_acc * (1.0f / ((float)N_ROWS * (float)DIM));
}

__global__ __launch_bounds__(256) void final_kernel(
    const float* __restrict__ embed_avg, const float* __restrict__ esumT,
    const float* __restrict__ smoothed, float* __restrict__ out_ne,
    float* __restrict__ out_nea) {
    __shared__ float t[32][33];
    int c0 = blockIdx.x * 32, d0 = blockIdx.y * 32;
    int tx = threadIdx.x & 31, ty = threadIdx.x >> 5;
    #pragma unroll
    for (int r = 0; r < 4; ++r)
        t[ty + r * 8][tx] = esumT[(size_t)(c0 + ty + r * 8) * DIM + d0 + tx];
    __syncthreads();
    #pragma unroll
    for (int r = 0; r < 4; ++r) {
        int d = d0 + ty + r * 8, c = c0 + tx;
        float es = t[tx][ty + r * 8];
        float ea = embed_avg[(size_t)d * NE + c] * DECAY + es * OMD;
        out_nea[(size_t)d * NE + c] = ea;
        out_ne[(size_t)d * NE + c] = ea / smoothed[c];
    }
}

extern "C" void kernel_launch(void* const* d_in, const int* in_sizes, int n_in,
                              void* d_out, int out_size, void* d_ws, size_t ws_size,
                              hipStream_t stream) {
    const float* input     = (const float*)d_in[0];
    const float* embed     = (const float*)d_in[1];
    const float* cs        = (const float*)d_in[2];
    const float* embed_avg = (const float*)d_in[3];
    float* out = (float*)d_out;
    float* ws  = (float*)d_ws;

    hipMemsetAsync(ws + WS_COUNTS, 0, (size_t)8192 * 4, stream);
    hipMemsetAsync(ws + WS_ENORM, 0, (size_t)8192 * 4, stream);
    hipMemsetAsync(ws + WS_LOSS, 0, (size_t)2 * 4, stream);

    convx_kernel<<<4096, 256, 0, stream>>>(input, (ushort*)(ws + WS_X2));
    prepB_kernel<<<dim3(256, 8), 256, 0, stream>>>(embed, (ushort*)(ws + WS_B2T),
                                                   ws + WS_ENORM);
    argmin_mfma<<<512, 512, 0, stream>>>(
        (const ushort*)(ws + WS_X2), (const ushort*)(ws + WS_B2T), ws + WS_ENORM,
        (int*)(ws + WS_PI));
    // X2 region is dead from here on -> overlay embedT / esumT
    transpose_kernel<<<dim3(256, 8), 256, 0, stream>>>(embed, ws + WS_EMBEDT);
    hipMemsetAsync(ws + WS_ESUMT, 0, (size_t)2097152 * 4, stream);
    rerank_gather<<<4096, 256, 0, stream>>>(input, ws + WS_EMBEDT, (int*)(ws + WS_PI),
                                            out + OUT_IND, out + OUT_Q,
                                            ws + WS_ESUMT, ws + WS_COUNTS, ws + WS_LOSS);
    ncs_kernel<<<32, 256, 0, stream>>>(cs, ws + WS_COUNTS, out + OUT_NCS, ws + WS_TOTAL);
    smooth_kernel<<<32, 256, 0, stream>>>(out + OUT_NCS, ws + WS_TOTAL, ws + WS_SMOOTH,
                                          ws + WS_LOSS, out + OUT_LOSS);
    final_kernel<<<dim3(256, 8), 256, 0, stream>>>(embed_avg, ws + WS_ESUMT, ws + WS_SMOOTH,
                                                   out + OUT_NE, out + OUT_NEA);
}

// Round 8
// 461.050 us; speedup vs baseline: 1.0666x; 1.0666x over previous
//
#include <hip/hip_runtime.h>
#include <hip/hip_bf16.h>
#include <float.h>
#include <stdint.h>

#define N_ROWS 16384
#define DIM 256
#define NE 8192
#define K2 768
#define DECAY 0.8f
#define OMD 0.2f
#define EPS 1e-5f
#define NPAN 8
#define NKT 24
#define NVT 96

// ---- ws layout (float element offsets) ----
#define WS_X2     0            // 16384*768 bf16 (6291456 floats)
#define WS_EMBEDT 0            // overlay (after argmin): 8192*256 f32
#define WS_ESUMT  2097152      // overlay (after argmin): 8192*256 f32
#define WS_B2T    6291456      // 8192*768 bf16 (3145728 floats)
#define WS_ENORM  9437184      // 8192
#define WS_COUNTS 9445376      // 8192
#define WS_SMOOTH 9453568      // 8192
#define WS_PI     9592832      // 16384*8 (int)
#define WS_LOSS   9740288      // 1
#define WS_TOTAL  9740289      // 1

// ---- out layout (float element offsets) ----
#define OUT_Q    0
#define OUT_IND  4194304
#define OUT_LOSS 4210688
#define OUT_NE   4210689
#define OUT_NCS  6307841
#define OUT_NEA  6316033

typedef __attribute__((ext_vector_type(8))) short bf16x8;
typedef __attribute__((ext_vector_type(4))) float f32x4;

static __device__ __forceinline__ ushort f2bf(float f) {
    uint32_t u = __float_as_uint(f);
    uint32_t r = (u + 0x7fffu + ((u >> 16) & 1u)) >> 16;
    return (ushort)r;
}
static __device__ __forceinline__ float bf2f(ushort h) {
    return __uint_as_float(((uint32_t)h) << 16);
}
static __device__ __forceinline__ void async16(void* lds, const void* g) {
    __builtin_amdgcn_global_load_lds(
        (const __attribute__((address_space(1))) uint32_t*)g,
        (__attribute__((address_space(3))) uint32_t*)lds, 16, 0, 0);
}

// x [16384][256] f32 -> X2 [16384][768] bf16 = [hi | lo | hi]
__global__ __launch_bounds__(256) void convx_kernel(const float* __restrict__ x,
                                                    ushort* __restrict__ X2) {
    int i = blockIdx.x * 256 + threadIdx.x;
    int row = i >> 6, q = (i & 63) * 4;
    float4 v = *(const float4*)&x[(size_t)row * 256 + q];
    ushort4 hi, lo;
    hi.x = f2bf(v.x); hi.y = f2bf(v.y); hi.z = f2bf(v.z); hi.w = f2bf(v.w);
    lo.x = f2bf(v.x - bf2f(hi.x)); lo.y = f2bf(v.y - bf2f(hi.y));
    lo.z = f2bf(v.z - bf2f(hi.z)); lo.w = f2bf(v.w - bf2f(hi.w));
    *(ushort4*)&X2[(size_t)row * K2 + q]       = hi;
    *(ushort4*)&X2[(size_t)row * K2 + 256 + q] = lo;
    *(ushort4*)&X2[(size_t)row * K2 + 512 + q] = hi;
}

// fused: embed [256][8192] -> B2T [8192][768] bf16 [hi|hi|lo]  +  enorm partials
__global__ __launch_bounds__(256) void prepB_kernel(const float* __restrict__ embed,
                                                    ushort* __restrict__ B2T,
                                                    float* __restrict__ enorm) {
    __shared__ float t[32][33];
    int c0 = blockIdx.x * 32, d0 = blockIdx.y * 32;
    int tx = threadIdx.x & 31, ty = threadIdx.x >> 5;
    #pragma unroll
    for (int r = 0; r < 4; ++r)
        t[ty + r * 8][tx] = embed[(size_t)(d0 + ty + r * 8) * NE + c0 + tx];
    __syncthreads();
    #pragma unroll
    for (int r = 0; r < 4; ++r) {
        int c = c0 + ty + r * 8, d = d0 + tx;
        float v = t[tx][ty + r * 8];
        ushort hi = f2bf(v);
        ushort lo = f2bf(v - bf2f(hi));
        B2T[(size_t)c * K2 + d]       = hi;
        B2T[(size_t)c * K2 + 256 + d] = hi;
        B2T[(size_t)c * K2 + 512 + d] = lo;
        float s = v * v;
        #pragma unroll
        for (int off = 16; off; off >>= 1) s += __shfl_down(s, off, 32);
        if (tx == 0) atomicAdd(&enorm[c], s);
    }
}

// embed [DIM][NE] -> embedT [NE][DIM]  (f32, for exact rerank; overlays X2)
__global__ __launch_bounds__(256) void transpose_kernel(const float* __restrict__ embed,
                                                        float* __restrict__ embedT) {
    __shared__ float t[32][33];
    int c0 = blockIdx.x * 32, d0 = blockIdx.y * 32;
    int tx = threadIdx.x & 31, ty = threadIdx.x >> 5;
    #pragma unroll
    for (int r = 0; r < 4; ++r)
        t[ty + r * 8][tx] = embed[(size_t)(d0 + ty + r * 8) * NE + c0 + tx];
    __syncthreads();
    #pragma unroll
    for (int r = 0; r < 4; ++r)
        embedT[(size_t)(c0 + ty + r * 8) * DIM + d0 + tx] = t[tx][ty + r * 8];
}

#define MFMA16(d, a, b) d = __builtin_amdgcn_mfma_f32_16x16x32_bf16(a, b, d, 0, 0, 0)

// 256x256-tile, 16 waves (64x64 each), BK=32, triple-buffered LDS (R6 pipeline).
// Conflict-free swizzle: bank-quad = (row&1, slot); sigma(row)=(row>>1)&3 makes
// each 8-lane group (fl=0..7, fixed fh) cover all 8 quads exactly once.
__global__ __launch_bounds__(1024, 4) void argmin_mfma(
    const ushort* __restrict__ X2, const ushort* __restrict__ B2T,
    const float* __restrict__ enorm, int* __restrict__ pi) {
    // ushort units: A bufs 3x8192 | B bufs 3x8192 | redv 2048 | redc 2048 | enS 2048
    __shared__ ushort smem[55296];
    float* const redv = (float*)(smem + 49152);
    int*   const redc = (int*)(smem + 51200);
    float* const enS  = (float*)(smem + 53248);

    const int lin = blockIdx.x;
    const int by = lin & 7, bx = lin >> 3;     // round-robin: XCD k owns panel k
    const int row0 = bx * 256, colb = by * 1024;

    const int tid = threadIdx.x;
    const int lane = tid & 63, wid = tid >> 6;
    const int fl = lane & 15, fh = lane >> 4;
    const int wr = wid >> 2, wc = wid & 3;

    enS[tid] = enorm[colb + tid];
    redv[tid] = FLT_MAX; redc[tid] = 0x7fffffff;

    // staging: row = tid>>2, lds slot = tid&3; source slot = (tid&3) ^ sigma(row),
    // sigma(row) = (row>>1)&3 = (tid>>3)&3
    const int srow = tid >> 2;
    const int swz = (tid & 3) ^ ((tid >> 3) & 3);
    const size_t aBase = (size_t)(row0 + srow) * K2 + swz * 8;
    const size_t bBase = (size_t)(colb + srow) * K2 + swz * 8;

    // prologue: tiles 0,1 -> bufs 0,1 (per-wave FIFO: A0,B0,A1,B1)
    async16(smem + 0 * 8192 + tid * 8, X2 + aBase);
    async16(smem + 24576 + 0 * 8192 + tid * 8, B2T + bBase);
    async16(smem + 1 * 8192 + tid * 8, X2 + aBase + 32);
    async16(smem + 24576 + 1 * 8192 + tid * 8, B2T + bBase + 32);

    // read: want k-slot fh of row base+fl -> lds slot fh ^ sigma(row) = fh ^ ((fl>>1)&3)
    const int xo = (fh ^ ((fl >> 1) & 3)) * 8;
    int aOff[4], bOff[4];
    #pragma unroll
    for (int m = 0; m < 4; ++m) aOff[m] = (wr * 64 + m * 16 + fl) * 32 + xo;
    #pragma unroll
    for (int n = 0; n < 4; ++n) bOff[n] = (wc * 64 + n * 16 + fl) * 32 + xo;

    f32x4 acc[4][4];
    #pragma unroll
    for (int m = 0; m < 4; ++m)
        #pragma unroll
        for (int n = 0; n < 4; ++n) acc[m][n] = (f32x4){0.f, 0.f, 0.f, 0.f};

    int cur = 0;
    #pragma unroll 1
    for (int vt = 0; vt < NVT; ++vt) {
        const int t = vt % NKT;
        int nv2 = vt + 2; if (nv2 >= NVT) nv2 -= NVT;
        const int nt2 = nv2 % NKT, nct2 = nv2 / NKT;
        int nbuf = cur + 2; if (nbuf >= 3) nbuf -= 3;

        // issue tile vt+2 into buf nbuf (freed at vt-1's end barrier)
        async16(smem + nbuf * 8192 + tid * 8, X2 + aBase + (size_t)nt2 * 32);
        async16(smem + 24576 + nbuf * 8192 + tid * 8,
                B2T + bBase + (size_t)nct2 * 196608 + (size_t)nt2 * 32);

        asm volatile("s_waitcnt vmcnt(4)" ::: "memory");
        __builtin_amdgcn_s_barrier();
        __builtin_amdgcn_sched_barrier(0);

        const ushort* Ac = smem + cur * 8192;
        const ushort* Bc = smem + 24576 + cur * 8192;
        bf16x8 af[4], bf[4];
        #pragma unroll
        for (int n = 0; n < 4; ++n) bf[n] = *(const bf16x8*)&Bc[bOff[n]];
        #pragma unroll
        for (int m = 0; m < 4; ++m) af[m] = *(const bf16x8*)&Ac[aOff[m]];

        __builtin_amdgcn_s_setprio(1);
        #pragma unroll
        for (int m = 0; m < 4; ++m)
            #pragma unroll
            for (int n = 0; n < 4; ++n)
                MFMA16(acc[m][n], af[m], bf[n]);
        __builtin_amdgcn_s_setprio(0);

        if (t == NKT - 1) {
            const int ct = vt / NKT;
            const int cb = colb + ct * 256 + wc * 64;
            float en[4];
            #pragma unroll
            for (int n = 0; n < 4; ++n) en[n] = enS[ct * 256 + wc * 64 + n * 16 + fl];
            #pragma unroll
            for (int m = 0; m < 4; ++m)
                #pragma unroll
                for (int r = 0; r < 4; ++r) {
                    float bv = FLT_MAX; int bc = 0x7fffffff;
                    #pragma unroll
                    for (int n = 0; n < 4; ++n) {
                        float s = __builtin_fmaf(-2.f, acc[m][n][r], en[n]);
                        int c = cb + n * 16 + fl;
                        if (s < bv) { bv = s; bc = c; }
                    }
                    #pragma unroll
                    for (int off = 1; off < 16; off <<= 1) {
                        float ov = __shfl_xor(bv, off, 64);
                        int oc = __shfl_xor(bc, off, 64);
                        if (ov < bv || (ov == bv && oc < bc)) { bv = ov; bc = oc; }
                    }
                    if (fl == 0) {
                        const int slot = (wr * 64 + m * 16 + fh * 4 + r) * 4 + wc;
                        float cv = redv[slot]; int cc = redc[slot];
                        if (bv < cv || (bv == cv && bc < cc)) {
                            redv[slot] = bv; redc[slot] = bc;
                        }
                    }
                }
            #pragma unroll
            for (int m = 0; m < 4; ++m)
                #pragma unroll
                for (int n = 0; n < 4; ++n) acc[m][n] = (f32x4){0.f, 0.f, 0.f, 0.f};
        }
        __builtin_amdgcn_s_barrier();
        __builtin_amdgcn_sched_barrier(0);
        cur = cur + 1 == 3 ? 0 : cur + 1;
    }

    asm volatile("s_waitcnt vmcnt(0) lgkmcnt(0)" ::: "memory");
    __builtin_amdgcn_s_barrier();
    if (tid < 256) {
        float bv = redv[tid * 4]; int bc = redc[tid * 4];
        #pragma unroll
        for (int w = 1; w < 4; ++w) {
            float v = redv[tid * 4 + w]; int c = redc[tid * 4 + w];
            if (v < bv || (v == bv && c < bc)) { bv = v; bc = c; }
        }
        pi[(size_t)(row0 + tid) * NPAN + by] = bc;
    }
}

// fused exact-f32 rerank of the 8 panel winners + quantize/loss/EMA-scatter
__global__ __launch_bounds__(256) void rerank_gather(
    const float* __restrict__ x, const float* __restrict__ embedT,
    const int* __restrict__ pi, float* __restrict__ out_ind,
    float* __restrict__ q_out, float* __restrict__ esumT,
    float* __restrict__ counts, float* __restrict__ loss_acc) {
    const int row = blockIdx.x * 4 + (threadIdx.x >> 6);
    const int lane = threadIdx.x & 63;
    float4 xv = *(const float4*)&x[(size_t)row * DIM + lane * 4];
    float bestd = FLT_MAX; int besti = 0;
    float4 ebest = {0.f, 0.f, 0.f, 0.f};
    #pragma unroll
    for (int p = 0; p < NPAN; ++p) {           // candidate indices strictly increase with p
        const int c = pi[(size_t)row * NPAN + p];
        float4 e = *(const float4*)&embedT[(size_t)c * DIM + lane * 4];
        float dx = e.x - xv.x, dy = e.y - xv.y, dz = e.z - xv.z, dw = e.w - xv.w;
        float s = dx * dx + dy * dy + dz * dz + dw * dw;
        #pragma unroll
        for (int off = 32; off; off >>= 1) s += __shfl_down(s, off);
        s = __shfl(s, 0);
        if (s < bestd) { bestd = s; besti = c; ebest = e; }
    }
    *(float4*)&q_out[(size_t)row * DIM + lane * 4] = ebest;
    __shared__ float ls[4];
    if (lane == 0) {
        out_ind[row] = (float)besti;
        ls[threadIdx.x >> 6] = bestd;
        atomicAdd(&counts[besti], 1.0f);
    }
    atomicAdd(&esumT[(size_t)besti * DIM + lane * 4 + 0], xv.x);
    atomicAdd(&esumT[(size_t)besti * DIM + lane * 4 + 1], xv.y);
    atomicAdd(&esumT[(size_t)besti * DIM + lane * 4 + 2], xv.z);
    atomicAdd(&esumT[(size_t)besti * DIM + lane * 4 + 3], xv.w);
    __syncthreads();
    if (threadIdx.x == 0) atomicAdd(loss_acc, ls[0] + ls[1] + ls[2] + ls[3]);
}

__global__ void ncs_kernel(const float* __restrict__ cs, const float* __restrict__ counts,
                           float* __restrict__ out_ncs, float* __restrict__ total) {
    int c = blockIdx.x * 256 + threadIdx.x;
    float v = cs[c] * DECAY + counts[c] * OMD;
    out_ncs[c] = v;
    float s = v;
    #pragma unroll
    for (int off = 32; off; off >>= 1) s += __shfl_down(s, off);
    __shared__ float bs[4];
    if ((threadIdx.x & 63) == 0) bs[threadIdx.x >> 6] = s;
    __syncthreads();
    if (threadIdx.x == 0) atomicAdd(total, bs[0] + bs[1] + bs[2] + bs[3]);
}

__global__ void smooth_kernel(const float* __restrict__ out_ncs, const float* __restrict__ total,
                              float* __restrict__ smoothed, const float* __restrict__ loss_acc,
                              float* __restrict__ out_loss) {
    int c = blockIdx.x * 256 + threadIdx.x;
    float tot = *total;
    float v = out_ncs[c];
    smoothed[c] = (v + EPS) / (tot + (float)NE * EPS) * tot;
    if (blockIdx.x == 0 && threadIdx.x == 0)
        *out_loss = *loss_acc * (1.0f / ((float)N_ROWS * (float)DIM));
}

__global__ __launch_bounds__(256) void final_kernel(
    const float* __restrict__ embed_avg, const float* __restrict__ esumT,
    const float* __restrict__ smoothed, float* __restrict__ out_ne,
    float* __restrict__ out_nea) {
    __shared__ float t[32][33];
    int c0 = blockIdx.x * 32, d0 = blockIdx.y * 32;
    int tx = threadIdx.x & 31, ty = threadIdx.x >> 5;
    #pragma unroll
    for (int r = 0; r < 4; ++r)
        t[ty + r * 8][tx] = esumT[(size_t)(c0 + ty + r * 8) * DIM + d0 + tx];
    __syncthreads();
    #pragma unroll
    for (int r = 0; r < 4; ++r) {
        int d = d0 + ty + r * 8, c = c0 + tx;
        float es = t[tx][ty + r * 8];
        float ea = embed_avg[(size_t)d * NE + c] * DECAY + es * OMD;
        out_nea[(size_t)d * NE + c] = ea;
        out_ne[(size_t)d * NE + c] = ea / smoothed[c];
    }
}

extern "C" void kernel_launch(void* const* d_in, const int* in_sizes, int n_in,
                              void* d_out, int out_size, void* d_ws, size_t ws_size,
                              hipStream_t stream) {
    const float* input     = (const float*)d_in[0];
    const float* embed     = (const float*)d_in[1];
    const float* cs        = (const float*)d_in[2];
    const float* embed_avg = (const float*)d_in[3];
    float* out = (float*)d_out;
    float* ws  = (float*)d_ws;

    hipMemsetAsync(ws + WS_COUNTS, 0, (size_t)8192 * 4, stream);
    hipMemsetAsync(ws + WS_ENORM, 0, (size_t)8192 * 4, stream);
    hipMemsetAsync(ws + WS_LOSS, 0, (size_t)2 * 4, stream);

    convx_kernel<<<4096, 256, 0, stream>>>(input, (ushort*)(ws + WS_X2));
    prepB_kernel<<<dim3(256, 8), 256, 0, stream>>>(embed, (ushort*)(ws + WS_B2T),
                                                   ws + WS_ENORM);
    argmin_mfma<<<512, 1024, 0, stream>>>(
        (const ushort*)(ws + WS_X2), (const ushort*)(ws + WS_B2T), ws + WS_ENORM,
        (int*)(ws + WS_PI));
    // X2 region is dead from here on -> overlay embedT / esumT
    transpose_kernel<<<dim3(256, 8), 256, 0, stream>>>(embed, ws + WS_EMBEDT);
    hipMemsetAsync(ws + WS_ESUMT, 0, (size_t)2097152 * 4, stream);
    rerank_gather<<<4096, 256, 0, stream>>>(input, ws + WS_EMBEDT, (int*)(ws + WS_PI),
                                            out + OUT_IND, out + OUT_Q,
                                            ws + WS_ESUMT, ws + WS_COUNTS, ws + WS_LOSS);
    ncs_kernel<<<32, 256, 0, stream>>>(cs, ws + WS_COUNTS, out + OUT_NCS, ws + WS_TOTAL);
    smooth_kernel<<<32, 256, 0, stream>>>(out + OUT_NCS, ws + WS_TOTAL, ws + WS_SMOOTH,
                                          ws + WS_LOSS, out + OUT_LOSS);
    final_kernel<<<dim3(256, 8), 256, 0, stream>>>(embed_avg, ws + WS_ESUMT, ws + WS_SMOOTH,
                                                   out + OUT_NE, out + OUT_NEA);
}

// Round 9
// 422.615 us; speedup vs baseline: 1.1636x; 1.0909x over previous
//
#include <hip/hip_runtime.h>
#include <hip/hip_bf16.h>
#include <float.h>
#include <stdint.h>

#define N_ROWS 16384
#define DIM 256
#define NE 8192
#define K2 768
#define DECAY 0.8f
#define OMD 0.2f
#define EPS 1e-5f
#define NPAN 8
#define NVT 24

// ---- ws layout (float element offsets) ----
#define WS_X2     0            // 16384*768 bf16 (6291456 floats)
#define WS_EMBEDT 0            // overlay (after argmin): 8192*256 f32
#define WS_ESUMT  2097152      // overlay (after argmin): 8192*256 f32
#define WS_B2T    6291456      // 8192*768 bf16 (3145728 floats)
#define WS_ENORM  9437184      // 8192
#define WS_COUNTS 9445376      // 8192
#define WS_SMOOTH 9453568      // 8192
#define WS_PV64   9461760      // 16384*8 u64 (262144 floats)
#define WS_LOSS   9740288      // 1
#define WS_TOTAL  9740289      // 1

// ---- out layout (float element offsets) ----
#define OUT_Q    0
#define OUT_IND  4194304
#define OUT_LOSS 4210688
#define OUT_NE   4210689
#define OUT_NCS  6307841
#define OUT_NEA  6316033

typedef __attribute__((ext_vector_type(8))) short bf16x8;
typedef __attribute__((ext_vector_type(4))) float f32x4;

static __device__ __forceinline__ ushort f2bf(float f) {
    uint32_t u = __float_as_uint(f);
    uint32_t r = (u + 0x7fffu + ((u >> 16) & 1u)) >> 16;
    return (ushort)r;
}
static __device__ __forceinline__ float bf2f(ushort h) {
    return __uint_as_float(((uint32_t)h) << 16);
}
static __device__ __forceinline__ void async16(void* lds, const void* g) {
    __builtin_amdgcn_global_load_lds(
        (const __attribute__((address_space(1))) uint32_t*)g,
        (__attribute__((address_space(3))) uint32_t*)lds, 16, 0, 0);
}

// x [16384][256] f32 -> X2 [16384][768] bf16 = [hi | lo | hi]
__global__ __launch_bounds__(256) void convx_kernel(const float* __restrict__ x,
                                                    ushort* __restrict__ X2) {
    int i = blockIdx.x * 256 + threadIdx.x;
    int row = i >> 6, q = (i & 63) * 4;
    float4 v = *(const float4*)&x[(size_t)row * 256 + q];
    ushort4 hi, lo;
    hi.x = f2bf(v.x); hi.y = f2bf(v.y); hi.z = f2bf(v.z); hi.w = f2bf(v.w);
    lo.x = f2bf(v.x - bf2f(hi.x)); lo.y = f2bf(v.y - bf2f(hi.y));
    lo.z = f2bf(v.z - bf2f(hi.z)); lo.w = f2bf(v.w - bf2f(hi.w));
    *(ushort4*)&X2[(size_t)row * K2 + q]       = hi;
    *(ushort4*)&X2[(size_t)row * K2 + 256 + q] = lo;
    *(ushort4*)&X2[(size_t)row * K2 + 512 + q] = hi;
}

// fused: embed [256][8192] -> B2T [8192][768] bf16 [hi|hi|lo]  +  enorm partials
__global__ __launch_bounds__(256) void prepB_kernel(const float* __restrict__ embed,
                                                    ushort* __restrict__ B2T,
                                                    float* __restrict__ enorm) {
    __shared__ float t[32][33];
    int c0 = blockIdx.x * 32, d0 = blockIdx.y * 32;
    int tx = threadIdx.x & 31, ty = threadIdx.x >> 5;
    #pragma unroll
    for (int r = 0; r < 4; ++r)
        t[ty + r * 8][tx] = embed[(size_t)(d0 + ty + r * 8) * NE + c0 + tx];
    __syncthreads();
    #pragma unroll
    for (int r = 0; r < 4; ++r) {
        int c = c0 + ty + r * 8, d = d0 + tx;
        float v = t[tx][ty + r * 8];
        ushort hi = f2bf(v);
        ushort lo = f2bf(v - bf2f(hi));
        B2T[(size_t)c * K2 + d]       = hi;
        B2T[(size_t)c * K2 + 256 + d] = hi;
        B2T[(size_t)c * K2 + 512 + d] = lo;
        float s = v * v;
        #pragma unroll
        for (int off = 16; off; off >>= 1) s += __shfl_down(s, off, 32);
        if (tx == 0) atomicAdd(&enorm[c], s);
    }
}

// embed [DIM][NE] -> embedT [NE][DIM]  (f32, for exact rerank; overlays X2)
__global__ __launch_bounds__(256) void transpose_kernel(const float* __restrict__ embed,
                                                        float* __restrict__ embedT) {
    __shared__ float t[32][33];
    int c0 = blockIdx.x * 32, d0 = blockIdx.y * 32;
    int tx = threadIdx.x & 31, ty = threadIdx.x >> 5;
    #pragma unroll
    for (int r = 0; r < 4; ++r)
        t[ty + r * 8][tx] = embed[(size_t)(d0 + ty + r * 8) * NE + c0 + tx];
    __syncthreads();
    #pragma unroll
    for (int r = 0; r < 4; ++r)
        embedT[(size_t)(c0 + ty + r * 8) * DIM + d0 + tx] = t[tx][ty + r * 8];
}

#define MFMA16(d, a, b) d = __builtin_amdgcn_mfma_f32_16x16x32_bf16(a, b, d, 0, 0, 0)

// 256x256 tile, 16 waves (64x64), BK=32, DOUBLE-buffered (73KB -> 2 blocks/CU).
// One column-tile per block (A read once); XCD-chunked mapping keeps the XCD's
// 3MB A slab L2-resident across all 32 col-tiles. Panel winners merged across
// the 4 col-tile blocks via packed-u64 atomicMin (monotone f32 key | index).
__global__ __launch_bounds__(1024, 2) void argmin_mfma(
    const ushort* __restrict__ X2, const ushort* __restrict__ B2T,
    const float* __restrict__ enorm, unsigned long long* __restrict__ pv64) {
    // ushort units: A bufs 2x8192 | B bufs 2x8192 | redv 2048 | redc 2048 | enS 512
    __shared__ ushort smem[37376];
    float* const redv = (float*)(smem + 32768);
    int*   const redc = (int*)(smem + 34816);
    float* const enS  = (float*)(smem + 36864);

    const int lin = blockIdx.x;
    const int xcd = lin & 7, q = lin >> 3;
    const int rb = q & 7, ct = q >> 3;           // XCD k: rows [k*2048,+2048) x all ct
    const int row0 = (xcd * 8 + rb) * 256;
    const int colb = ct * 256;
    const int panel = ct >> 2;

    const int tid = threadIdx.x;
    const int lane = tid & 63, wid = tid >> 6;
    const int fl = lane & 15, fh = lane >> 4;
    const int wr = wid >> 2, wc = wid & 3;

    if (tid < 256) enS[tid] = enorm[colb + tid];
    redv[tid] = FLT_MAX; redc[tid] = 0x7fffffff;

    // staging: row = tid>>2, lds slot = tid&3; source slot = (tid&3) ^ ((row>>1)&3)
    const int srow = tid >> 2;
    const int swz = (tid & 3) ^ ((tid >> 3) & 3);
    const size_t aBase = (size_t)(row0 + srow) * K2 + swz * 8;
    const size_t bBase = (size_t)(colb + srow) * K2 + swz * 8;

    // prologue: tile 0 -> buf 0
    async16(smem + 0 * 8192 + tid * 8, X2 + aBase);
    async16(smem + 16384 + 0 * 8192 + tid * 8, B2T + bBase);

    // read: k-slot fh of row base+fl -> lds slot fh ^ ((fl>>1)&3)
    const int xo = (fh ^ ((fl >> 1) & 3)) * 8;
    int aOff[4], bOff[4];
    #pragma unroll
    for (int m = 0; m < 4; ++m) aOff[m] = (wr * 64 + m * 16 + fl) * 32 + xo;
    #pragma unroll
    for (int n = 0; n < 4; ++n) bOff[n] = (wc * 64 + n * 16 + fl) * 32 + xo;

    f32x4 acc[4][4];
    #pragma unroll
    for (int m = 0; m < 4; ++m)
        #pragma unroll
        for (int n = 0; n < 4; ++n) acc[m][n] = (f32x4){0.f, 0.f, 0.f, 0.f};

    #pragma unroll 1
    for (int vt = 0; vt < NVT; ++vt) {
        int nv = vt + 1; if (nv == NVT) nv = 0;   // wrap issue keeps vmcnt math uniform
        const int nbuf = nv & 1, cbuf = vt & 1;

        // issue tile vt+1 into the other buffer (its last reader barrier-passed)
        async16(smem + nbuf * 8192 + tid * 8, X2 + aBase + (size_t)nv * 32);
        async16(smem + 16384 + nbuf * 8192 + tid * 8, B2T + bBase + (size_t)nv * 32);

        asm volatile("s_waitcnt vmcnt(2)" ::: "memory");   // retire tile vt's 2 loads
        __builtin_amdgcn_s_barrier();
        __builtin_amdgcn_sched_barrier(0);

        const ushort* Ac = smem + cbuf * 8192;
        const ushort* Bc = smem + 16384 + cbuf * 8192;
        bf16x8 af[4], bf[4];
        #pragma unroll
        for (int n = 0; n < 4; ++n) bf[n] = *(const bf16x8*)&Bc[bOff[n]];
        #pragma unroll
        for (int m = 0; m < 4; ++m) af[m] = *(const bf16x8*)&Ac[aOff[m]];

        __builtin_amdgcn_s_setprio(1);
        #pragma unroll
        for (int m = 0; m < 4; ++m)
            #pragma unroll
            for (int n = 0; n < 4; ++n)
                MFMA16(acc[m][n], af[m], bf[n]);
        __builtin_amdgcn_s_setprio(0);

        __builtin_amdgcn_s_barrier();
        __builtin_amdgcn_sched_barrier(0);
    }

    // fold: per-thread best over its 16 columns, then 16-lane argmin reduce
    float en[4];
    #pragma unroll
    for (int n = 0; n < 4; ++n) en[n] = enS[wc * 64 + n * 16 + fl];
    #pragma unroll
    for (int m = 0; m < 4; ++m)
        #pragma unroll
        for (int r = 0; r < 4; ++r) {
            float bv = FLT_MAX; int bc = 0x7fffffff;
            #pragma unroll
            for (int n = 0; n < 4; ++n) {
                float s = __builtin_fmaf(-2.f, acc[m][n][r], en[n]);
                int c = colb + wc * 64 + n * 16 + fl;
                if (s < bv) { bv = s; bc = c; }
            }
            #pragma unroll
            for (int off = 1; off < 16; off <<= 1) {
                float ov = __shfl_xor(bv, off, 64);
                int oc = __shfl_xor(bc, off, 64);
                if (ov < bv || (ov == bv && oc < bc)) { bv = ov; bc = oc; }
            }
            if (fl == 0) {
                const int slot = (wr * 64 + m * 16 + fh * 4 + r) * 4 + wc;
                redv[slot] = bv; redc[slot] = bc;
            }
        }
    __syncthreads();
    if (tid < 256) {
        float bv = redv[tid * 4]; int bc = redc[tid * 4];
        #pragma unroll
        for (int w = 1; w < 4; ++w) {
            float v = redv[tid * 4 + w]; int c = redc[tid * 4 + w];
            if (v < bv || (v == bv && c < bc)) { bv = v; bc = c; }
        }
        // monotone key pack: min over (value, index)
        unsigned int u = __float_as_uint(bv);
        unsigned int key = (u & 0x80000000u) ? ~u : (u | 0x80000000u);
        unsigned long long pk = ((unsigned long long)key << 32) | (unsigned int)bc;
        atomicMin(&pv64[(size_t)(row0 + tid) * NPAN + panel], pk);
    }
}

// fused exact-f32 rerank of the 8 panel winners + quantize/loss/EMA-scatter
__global__ __launch_bounds__(256) void rerank_gather(
    const float* __restrict__ x, const float* __restrict__ embedT,
    const unsigned long long* __restrict__ pv64, float* __restrict__ out_ind,
    float* __restrict__ q_out, float* __restrict__ esumT,
    float* __restrict__ counts, float* __restrict__ loss_acc) {
    const int row = blockIdx.x * 4 + (threadIdx.x >> 6);
    const int lane = threadIdx.x & 63;
    float4 xv = *(const float4*)&x[(size_t)row * DIM + lane * 4];
    float bestd = FLT_MAX; int besti = 0;
    float4 ebest = {0.f, 0.f, 0.f, 0.f};
    #pragma unroll
    for (int p = 0; p < NPAN; ++p) {           // candidate indices strictly increase with p
        const int c = (int)(unsigned int)(pv64[(size_t)row * NPAN + p] & 0xffffffffull);
        float4 e = *(const float4*)&embedT[(size_t)c * DIM + lane * 4];
        float dx = e.x - xv.x, dy = e.y - xv.y, dz = e.z - xv.z, dw = e.w - xv.w;
        float s = dx * dx + dy * dy + dz * dz + dw * dw;
        #pragma unroll
        for (int off = 32; off; off >>= 1) s += __shfl_down(s, off);
        s = __shfl(s, 0);
        if (s < bestd) { bestd = s; besti = c; ebest = e; }
    }
    *(float4*)&q_out[(size_t)row * DIM + lane * 4] = ebest;
    __shared__ float ls[4];
    if (lane == 0) {
        out_ind[row] = (float)besti;
        ls[threadIdx.x >> 6] = bestd;
        atomicAdd(&counts[besti], 1.0f);
    }
    atomicAdd(&esumT[(size_t)besti * DIM + lane * 4 + 0], xv.x);
    atomicAdd(&esumT[(size_t)besti * DIM + lane * 4 + 1], xv.y);
    atomicAdd(&esumT[(size_t)besti * DIM + lane * 4 + 2], xv.z);
    atomicAdd(&esumT[(size_t)besti * DIM + lane * 4 + 3], xv.w);
    __syncthreads();
    if (threadIdx.x == 0) atomicAdd(loss_acc, ls[0] + ls[1] + ls[2] + ls[3]);
}

__global__ void ncs_kernel(const float* __restrict__ cs, const float* __restrict__ counts,
                           float* __restrict__ out_ncs, float* __restrict__ total) {
    int c = blockIdx.x * 256 + threadIdx.x;
    float v = cs[c] * DECAY + counts[c] * OMD;
    out_ncs[c] = v;
    float s = v;
    #pragma unroll
    for (int off = 32; off; off >>= 1) s += __shfl_down(s, off);
    __shared__ float bs[4];
    if ((threadIdx.x & 63) == 0) bs[threadIdx.x >> 6] = s;
    __syncthreads();
    if (threadIdx.x == 0) atomicAdd(total, bs[0] + bs[1] + bs[2] + bs[3]);
}

__global__ void smooth_kernel(const float* __restrict__ out_ncs, const float* __restrict__ total,
                              float* __restrict__ smoothed, const float* __restrict__ loss_acc,
                              float* __restrict__ out_loss) {
    int c = blockIdx.x * 256 + threadIdx.x;
    float tot = *total;
    float v = out_ncs[c];
    smoothed[c] = (v + EPS) / (tot + (float)NE * EPS) * tot;
    if (blockIdx.x == 0 && threadIdx.x == 0)
        *out_loss = *loss_acc * (1.0f / ((float)N_ROWS * (float)DIM));
}

__global__ __launch_bounds__(256) void final_kernel(
    const float* __restrict__ embed_avg, const float* __restrict__ esumT,
    const float* __restrict__ smoothed, float* __restrict__ out_ne,
    float* __restrict__ out_nea) {
    __shared__ float t[32][33];
    int c0 = blockIdx.x * 32, d0 = blockIdx.y * 32;
    int tx = threadIdx.x & 31, ty = threadIdx.x >> 5;
    #pragma unroll
    for (int r = 0; r < 4; ++r)
        t[ty + r * 8][tx] = esumT[(size_t)(c0 + ty + r * 8) * DIM + d0 + tx];
    __syncthreads();
    #pragma unroll
    for (int r = 0; r < 4; ++r) {
        int d = d0 + ty + r * 8, c = c0 + tx;
        float es = t[tx][ty + r * 8];
        float ea = embed_avg[(size_t)d * NE + c] * DECAY + es * OMD;
        out_nea[(size_t)d * NE + c] = ea;
        out_ne[(size_t)d * NE + c] = ea / smoothed[c];
    }
}

extern "C" void kernel_launch(void* const* d_in, const int* in_sizes, int n_in,
                              void* d_out, int out_size, void* d_ws, size_t ws_size,
                              hipStream_t stream) {
    const float* input     = (const float*)d_in[0];
    const float* embed     = (const float*)d_in[1];
    const float* cs        = (const float*)d_in[2];
    const float* embed_avg = (const float*)d_in[3];
    float* out = (float*)d_out;
    float* ws  = (float*)d_ws;

    hipMemsetAsync(ws + WS_COUNTS, 0, (size_t)8192 * 4, stream);
    hipMemsetAsync(ws + WS_ENORM, 0, (size_t)8192 * 4, stream);
    hipMemsetAsync(ws + WS_LOSS, 0, (size_t)2 * 4, stream);
    hipMemsetAsync(ws + WS_PV64, 0xFF, (size_t)16384 * NPAN * 8, stream);

    convx_kernel<<<4096, 256, 0, stream>>>(input, (ushort*)(ws + WS_X2));
    prepB_kernel<<<dim3(256, 8), 256, 0, stream>>>(embed, (ushort*)(ws + WS_B2T),
                                                   ws + WS_ENORM);
    argmin_mfma<<<2048, 1024, 0, stream>>>(
        (const ushort*)(ws + WS_X2), (const ushort*)(ws + WS_B2T), ws + WS_ENORM,
        (unsigned long long*)(ws + WS_PV64));
    // X2 region is dead from here on -> overlay embedT / esumT
    transpose_kernel<<<dim3(256, 8), 256, 0, stream>>>(embed, ws + WS_EMBEDT);
    hipMemsetAsync(ws + WS_ESUMT, 0, (size_t)2097152 * 4, stream);
    rerank_gather<<<4096, 256, 0, stream>>>(input, ws + WS_EMBEDT,
                                            (const unsigned long long*)(ws + WS_PV64),
                                            out + OUT_IND, out + OUT_Q,
                                            ws + WS_ESUMT, ws + WS_COUNTS, ws + WS_LOSS);
    ncs_kernel<<<32, 256, 0, stream>>>(cs, ws + WS_COUNTS, out + OUT_NCS, ws + WS_TOTAL);
    smooth_kernel<<<32, 256, 0, stream>>>(out + OUT_NCS, ws + WS_TOTAL, ws + WS_SMOOTH,
                                          ws + WS_LOSS, out + OUT_LOSS);
    final_kernel<<<dim3(256, 8), 256, 0, stream>>>(embed_avg, ws + WS_ESUMT, ws + WS_SMOOTH,
                                                   out + OUT_NE, out + OUT_NEA);
}

// Round 10
// 414.691 us; speedup vs baseline: 1.1859x; 1.0191x over previous
//
#include <hip/hip_runtime.h>
#include <hip/hip_bf16.h>
#include <float.h>
#include <stdint.h>

#define N_ROWS 16384
#define DIM 256
#define NE 8192
#define K2 768
#define DECAY 0.8f
#define OMD 0.2f
#define EPS 1e-5f
#define NPAN 8
#define NVT 24

// ---- ws layout (float element offsets) ----
#define WS_X2     0            // 16384*768 bf16 (6291456 floats)
#define WS_EMBEDT 0            // overlay (after argmin): 8192*256 f32
#define WS_ESUMT  2097152      // overlay (after argmin): 8192*256 f32
#define WS_B2T    6291456      // 8192*768 bf16 (3145728 floats)
#define WS_ENORM  9437184      // 8192
#define WS_COUNTS 9445376      // 8192
#define WS_SMOOTH 9453568      // 8192
#define WS_PV64   9461760      // 16384*8 u64 (262144 floats)
#define WS_LOSS   9740288      // 1
#define WS_TOTAL  9740289      // 1

// ---- out layout (float element offsets) ----
#define OUT_Q    0
#define OUT_IND  4194304
#define OUT_LOSS 4210688
#define OUT_NE   4210689
#define OUT_NCS  6307841
#define OUT_NEA  6316033

typedef __attribute__((ext_vector_type(8))) short bf16x8;
typedef __attribute__((ext_vector_type(4))) float f32x4;

static __device__ __forceinline__ ushort f2bf(float f) {
    uint32_t u = __float_as_uint(f);
    uint32_t r = (u + 0x7fffu + ((u >> 16) & 1u)) >> 16;
    return (ushort)r;
}
static __device__ __forceinline__ float bf2f(ushort h) {
    return __uint_as_float(((uint32_t)h) << 16);
}
static __device__ __forceinline__ void async16(void* lds, const void* g) {
    __builtin_amdgcn_global_load_lds(
        (const __attribute__((address_space(1))) uint32_t*)g,
        (__attribute__((address_space(3))) uint32_t*)lds, 16, 0, 0);
}

// x [16384][256] f32 -> X2 [16384][768] bf16 = [hi | lo | hi]
__global__ __launch_bounds__(256) void convx_kernel(const float* __restrict__ x,
                                                    ushort* __restrict__ X2) {
    int i = blockIdx.x * 256 + threadIdx.x;
    int row = i >> 6, q = (i & 63) * 4;
    float4 v = *(const float4*)&x[(size_t)row * 256 + q];
    ushort4 hi, lo;
    hi.x = f2bf(v.x); hi.y = f2bf(v.y); hi.z = f2bf(v.z); hi.w = f2bf(v.w);
    lo.x = f2bf(v.x - bf2f(hi.x)); lo.y = f2bf(v.y - bf2f(hi.y));
    lo.z = f2bf(v.z - bf2f(hi.z)); lo.w = f2bf(v.w - bf2f(hi.w));
    *(ushort4*)&X2[(size_t)row * K2 + q]       = hi;
    *(ushort4*)&X2[(size_t)row * K2 + 256 + q] = lo;
    *(ushort4*)&X2[(size_t)row * K2 + 512 + q] = hi;
}

// fused: embed [256][8192] -> B2T [8192][768] bf16 [hi|hi|lo]  +  enorm partials
__global__ __launch_bounds__(256) void prepB_kernel(const float* __restrict__ embed,
                                                    ushort* __restrict__ B2T,
                                                    float* __restrict__ enorm) {
    __shared__ float t[32][33];
    int c0 = blockIdx.x * 32, d0 = blockIdx.y * 32;
    int tx = threadIdx.x & 31, ty = threadIdx.x >> 5;
    #pragma unroll
    for (int r = 0; r < 4; ++r)
        t[ty + r * 8][tx] = embed[(size_t)(d0 + ty + r * 8) * NE + c0 + tx];
    __syncthreads();
    #pragma unroll
    for (int r = 0; r < 4; ++r) {
        int c = c0 + ty + r * 8, d = d0 + tx;
        float v = t[tx][ty + r * 8];
        ushort hi = f2bf(v);
        ushort lo = f2bf(v - bf2f(hi));
        B2T[(size_t)c * K2 + d]       = hi;
        B2T[(size_t)c * K2 + 256 + d] = hi;
        B2T[(size_t)c * K2 + 512 + d] = lo;
        float s = v * v;
        #pragma unroll
        for (int off = 16; off; off >>= 1) s += __shfl_down(s, off, 32);
        if (tx == 0) atomicAdd(&enorm[c], s);
    }
}

// embed [DIM][NE] -> embedT [NE][DIM]  (f32, for exact rerank; overlays X2)
__global__ __launch_bounds__(256) void transpose_kernel(const float* __restrict__ embed,
                                                        float* __restrict__ embedT) {
    __shared__ float t[32][33];
    int c0 = blockIdx.x * 32, d0 = blockIdx.y * 32;
    int tx = threadIdx.x & 31, ty = threadIdx.x >> 5;
    #pragma unroll
    for (int r = 0; r < 4; ++r)
        t[ty + r * 8][tx] = embed[(size_t)(d0 + ty + r * 8) * NE + c0 + tx];
    __syncthreads();
    #pragma unroll
    for (int r = 0; r < 4; ++r)
        embedT[(size_t)(c0 + ty + r * 8) * DIM + d0 + tx] = t[tx][ty + r * 8];
}

#define MFMA16(d, a, b) d = __builtin_amdgcn_mfma_f32_16x16x32_bf16(a, b, d, 0, 0, 0)

// 128x256 block tile, 8 waves (64x64), BK=32, double-buffered, 49KB LDS
// -> 3 blocks/CU co-resident (the R9 bottleneck was 1-block lockstep).
// Fold scratch overlays the dead A-buffers after a vmcnt(0) drain.
__global__ __launch_bounds__(512) void argmin_mfma(
    const ushort* __restrict__ X2, const ushort* __restrict__ B2T,
    const float* __restrict__ enorm, unsigned long long* __restrict__ pv64) {
    // ushort units: A0 @0 (4096) | A1 @4096 | B0 @8192 (8192) | B1 @16384 | enS @24576 (512)
    __shared__ ushort smem[25088];
    float* const enS = (float*)(smem + 24576);

    const int lin = blockIdx.x;
    const int xcd = lin & 7, q = lin >> 3;
    const int rb = q & 15, ct = q >> 4;          // XCD k: rows [k*2048,+2048) x all ct
    const int row0 = (xcd * 16 + rb) * 128;
    const int colb = ct * 256;
    const int panel = ct >> 2;

    const int tid = threadIdx.x;
    const int lane = tid & 63, wid = tid >> 6;
    const int fl = lane & 15, fh = lane >> 4;
    const int wr = wid >> 2, wc = wid & 3;       // 2 x 4 waves of 64x64

    if (tid < 256) enS[tid] = enorm[colb + tid];
    __builtin_amdgcn_sched_barrier(0);

    // staging: chunk c: row = c>>2, lds slot = c&3; source slot = (c&3)^((c>>3)&3)
    const int srow = tid >> 2;
    const int swz = (tid & 3) ^ ((tid >> 3) & 3);
    const size_t aBase = (size_t)(row0 + srow) * K2 + swz * 8;        // A rows 0..127
    const size_t bBase = (size_t)(colb + srow) * K2 + swz * 8;        // B rows 0..127
    const size_t bBase2 = bBase + (size_t)128 * K2;                   // B rows 128..255

    // prologue: tile 0 -> buf 0 (3 loads/thread)
    async16(smem + tid * 8, X2 + aBase);
    async16(smem + 8192 + tid * 8, B2T + bBase);
    async16(smem + 8192 + (tid + 512) * 8, B2T + bBase2);

    // read: k-slot fh of row base+fl -> lds slot fh ^ ((fl>>1)&3)
    const int xo = (fh ^ ((fl >> 1) & 3)) * 8;
    int aOff[4], bOff[4];
    #pragma unroll
    for (int m = 0; m < 4; ++m) aOff[m] = (wr * 64 + m * 16 + fl) * 32 + xo;
    #pragma unroll
    for (int n = 0; n < 4; ++n) bOff[n] = (wc * 64 + n * 16 + fl) * 32 + xo;

    f32x4 acc[4][4];
    #pragma unroll
    for (int m = 0; m < 4; ++m)
        #pragma unroll
        for (int n = 0; n < 4; ++n) acc[m][n] = (f32x4){0.f, 0.f, 0.f, 0.f};

    #pragma unroll 1
    for (int vt = 0; vt < NVT; ++vt) {
        int nv = vt + 1; if (nv == NVT) nv = 0;   // wrap issue keeps vmcnt math uniform
        const int nbuf = nv & 1, cbuf = vt & 1;

        // issue tile vt+1 into the other buffer (its last reader barrier-passed)
        async16(smem + nbuf * 4096 + tid * 8, X2 + aBase + (size_t)nv * 32);
        async16(smem + 8192 + nbuf * 8192 + tid * 8, B2T + bBase + (size_t)nv * 32);
        async16(smem + 8192 + nbuf * 8192 + (tid + 512) * 8, B2T + bBase2 + (size_t)nv * 32);

        asm volatile("s_waitcnt vmcnt(3)" ::: "memory");   // retire tile vt's 3 loads
        __builtin_amdgcn_s_barrier();
        __builtin_amdgcn_sched_barrier(0);

        const ushort* Ac = smem + cbuf * 4096;
        const ushort* Bc = smem + 8192 + cbuf * 8192;
        bf16x8 af[4], bf[4];
        #pragma unroll
        for (int n = 0; n < 4; ++n) bf[n] = *(const bf16x8*)&Bc[bOff[n]];
        #pragma unroll
        for (int m = 0; m < 4; ++m) af[m] = *(const bf16x8*)&Ac[aOff[m]];

        __builtin_amdgcn_s_setprio(1);
        #pragma unroll
        for (int m = 0; m < 4; ++m)
            #pragma unroll
            for (int n = 0; n < 4; ++n)
                MFMA16(acc[m][n], af[m], bf[n]);
        __builtin_amdgcn_s_setprio(0);

        __builtin_amdgcn_s_barrier();
        __builtin_amdgcn_sched_barrier(0);
    }

    // drain wrap-issued loads, then overlay fold scratch on the dead A-buffers
    asm volatile("s_waitcnt vmcnt(0) lgkmcnt(0)" ::: "memory");
    __builtin_amdgcn_s_barrier();
    float* const redv = (float*)smem;            // 512 floats  (A0 region, dead)
    int*   const redc = (int*)(smem + 2048);     // 512 ints    (A0/A1 region, dead)

    float en[4];
    #pragma unroll
    for (int n = 0; n < 4; ++n) en[n] = enS[wc * 64 + n * 16 + fl];
    #pragma unroll
    for (int m = 0; m < 4; ++m)
        #pragma unroll
        for (int r = 0; r < 4; ++r) {
            float bv = FLT_MAX; int bc = 0x7fffffff;
            #pragma unroll
            for (int n = 0; n < 4; ++n) {
                float s = __builtin_fmaf(-2.f, acc[m][n][r], en[n]);
                int c = colb + wc * 64 + n * 16 + fl;
                if (s < bv) { bv = s; bc = c; }
            }
            #pragma unroll
            for (int off = 1; off < 16; off <<= 1) {
                float ov = __shfl_xor(bv, off, 64);
                int oc = __shfl_xor(bc, off, 64);
                if (ov < bv || (ov == bv && oc < bc)) { bv = ov; bc = oc; }
            }
            if (fl == 0) {
                const int slot = (wr * 64 + m * 16 + fh * 4 + r) * 4 + wc;
                redv[slot] = bv; redc[slot] = bc;
            }
        }
    __syncthreads();
    if (tid < 128) {
        float bv = redv[tid * 4]; int bc = redc[tid * 4];
        #pragma unroll
        for (int w = 1; w < 4; ++w) {
            float v = redv[tid * 4 + w]; int c = redc[tid * 4 + w];
            if (v < bv || (v == bv && c < bc)) { bv = v; bc = c; }
        }
        // monotone key pack: min over (value, index)
        unsigned int u = __float_as_uint(bv);
        unsigned int key = (u & 0x80000000u) ? ~u : (u | 0x80000000u);
        unsigned long long pk = ((unsigned long long)key << 32) | (unsigned int)bc;
        atomicMin(&pv64[(size_t)(row0 + tid) * NPAN + panel], pk);
    }
}

// fused exact-f32 rerank of the 8 panel winners + quantize/loss/EMA-scatter
__global__ __launch_bounds__(256) void rerank_gather(
    const float* __restrict__ x, const float* __restrict__ embedT,
    const unsigned long long* __restrict__ pv64, float* __restrict__ out_ind,
    float* __restrict__ q_out, float* __restrict__ esumT,
    float* __restrict__ counts, float* __restrict__ loss_acc) {
    const int row = blockIdx.x * 4 + (threadIdx.x >> 6);
    const int lane = threadIdx.x & 63;
    float4 xv = *(const float4*)&x[(size_t)row * DIM + lane * 4];
    float bestd = FLT_MAX; int besti = 0;
    float4 ebest = {0.f, 0.f, 0.f, 0.f};
    #pragma unroll
    for (int p = 0; p < NPAN; ++p) {           // candidate indices strictly increase with p
        const int c = (int)(unsigned int)(pv64[(size_t)row * NPAN + p] & 0xffffffffull);
        float4 e = *(const float4*)&embedT[(size_t)c * DIM + lane * 4];
        float dx = e.x - xv.x, dy = e.y - xv.y, dz = e.z - xv.z, dw = e.w - xv.w;
        float s = dx * dx + dy * dy + dz * dz + dw * dw;
        #pragma unroll
        for (int off = 32; off; off >>= 1) s += __shfl_down(s, off);
        s = __shfl(s, 0);
        if (s < bestd) { bestd = s; besti = c; ebest = e; }
    }
    *(float4*)&q_out[(size_t)row * DIM + lane * 4] = ebest;
    __shared__ float ls[4];
    if (lane == 0) {
        out_ind[row] = (float)besti;
        ls[threadIdx.x >> 6] = bestd;
        atomicAdd(&counts[besti], 1.0f);
    }
    atomicAdd(&esumT[(size_t)besti * DIM + lane * 4 + 0], xv.x);
    atomicAdd(&esumT[(size_t)besti * DIM + lane * 4 + 1], xv.y);
    atomicAdd(&esumT[(size_t)besti * DIM + lane * 4 + 2], xv.z);
    atomicAdd(&esumT[(size_t)besti * DIM + lane * 4 + 3], xv.w);
    __syncthreads();
    if (threadIdx.x == 0) atomicAdd(loss_acc, ls[0] + ls[1] + ls[2] + ls[3]);
}

__global__ void ncs_kernel(const float* __restrict__ cs, const float* __restrict__ counts,
                           float* __restrict__ out_ncs, float* __restrict__ total) {
    int c = blockIdx.x * 256 + threadIdx.x;
    float v = cs[c] * DECAY + counts[c] * OMD;
    out_ncs[c] = v;
    float s = v;
    #pragma unroll
    for (int off = 32; off; off >>= 1) s += __shfl_down(s, off);
    __shared__ float bs[4];
    if ((threadIdx.x & 63) == 0) bs[threadIdx.x >> 6] = s;
    __syncthreads();
    if (threadIdx.x == 0) atomicAdd(total, bs[0] + bs[1] + bs[2] + bs[3]);
}

__global__ void smooth_kernel(const float* __restrict__ out_ncs, const float* __restrict__ total,
                              float* __restrict__ smoothed, const float* __restrict__ loss_acc,
                              float* __restrict__ out_loss) {
    int c = blockIdx.x * 256 + threadIdx.x;
    float tot = *total;
    float v = out_ncs[c];
    smoothed[c] = (v + EPS) / (tot + (float)NE * EPS) * tot;
    if (blockIdx.x == 0 && threadIdx.x == 0)
        *out_loss = *loss_acc * (1.0f / ((float)N_ROWS * (float)DIM));
}

__global__ __launch_bounds__(256) void final_kernel(
    const float* __restrict__ embed_avg, const float* __restrict__ esumT,
    const float* __restrict__ smoothed, float* __restrict__ out_ne,
    float* __restrict__ out_nea) {
    __shared__ float t[32][33];
    int c0 = blockIdx.x * 32, d0 = blockIdx.y * 32;
    int tx = threadIdx.x & 31, ty = threadIdx.x >> 5;
    #pragma unroll
    for (int r = 0; r < 4; ++r)
        t[ty + r * 8][tx] = esumT[(size_t)(c0 + ty + r * 8) * DIM + d0 + tx];
    __syncthreads();
    #pragma unroll
    for (int r = 0; r < 4; ++r) {
        int d = d0 + ty + r * 8, c = c0 + tx;
        float es = t[tx][ty + r * 8];
        float ea = embed_avg[(size_t)d * NE + c] * DECAY + es * OMD;
        out_nea[(size_t)d * NE + c] = ea;
        out_ne[(size_t)d * NE + c] = ea / smoothed[c];
    }
}

extern "C" void kernel_launch(void* const* d_in, const int* in_sizes, int n_in,
                              void* d_out, int out_size, void* d_ws, size_t ws_size,
                              hipStream_t stream) {
    const float* input     = (const float*)d_in[0];
    const float* embed     = (const float*)d_in[1];
    const float* cs        = (const float*)d_in[2];
    const float* embed_avg = (const float*)d_in[3];
    float* out = (float*)d_out;
    float* ws  = (float*)d_ws;

    hipMemsetAsync(ws + WS_COUNTS, 0, (size_t)8192 * 4, stream);
    hipMemsetAsync(ws + WS_ENORM, 0, (size_t)8192 * 4, stream);
    hipMemsetAsync(ws + WS_LOSS, 0, (size_t)2 * 4, stream);
    hipMemsetAsync(ws + WS_PV64, 0xFF, (size_t)16384 * NPAN * 8, stream);

    convx_kernel<<<4096, 256, 0, stream>>>(input, (ushort*)(ws + WS_X2));
    prepB_kernel<<<dim3(256, 8), 256, 0, stream>>>(embed, (ushort*)(ws + WS_B2T),
                                                   ws + WS_ENORM);
    argmin_mfma<<<4096, 512, 0, stream>>>(
        (const ushort*)(ws + WS_X2), (const ushort*)(ws + WS_B2T), ws + WS_ENORM,
        (unsigned long long*)(ws + WS_PV64));
    // X2 region is dead from here on -> overlay embedT / esumT
    transpose_kernel<<<dim3(256, 8), 256, 0, stream>>>(embed, ws + WS_EMBEDT);
    hipMemsetAsync(ws + WS_ESUMT, 0, (size_t)2097152 * 4, stream);
    rerank_gather<<<4096, 256, 0, stream>>>(input, ws + WS_EMBEDT,
                                            (const unsigned long long*)(ws + WS_PV64),
                                            out + OUT_IND, out + OUT_Q,
                                            ws + WS_ESUMT, ws + WS_COUNTS, ws + WS_LOSS);
    ncs_kernel<<<32, 256, 0, stream>>>(cs, ws + WS_COUNTS, out + OUT_NCS, ws + WS_TOTAL);
    smooth_kernel<<<32, 256, 0, stream>>>(out + OUT_NCS, ws + WS_TOTAL, ws + WS_SMOOTH,
                                          ws + WS_LOSS, out + OUT_LOSS);
    final_kernel<<<dim3(256, 8), 256, 0, stream>>>(embed_avg, ws + WS_ESUMT, ws + WS_SMOOTH,
                                                   out + OUT_NE, out + OUT_NEA);
}